// Round 10
// baseline (617.873 us; speedup 1.0000x reference)
//
#include <hip/hip_runtime.h>
#include <hip/hip_bf16.h>

#define NN 50000
#define EE 800000
#define NTILES 12500
#define BPG 512                     // blocks per graph

typedef __attribute__((ext_vector_type(8))) short bf16x8;
typedef __attribute__((ext_vector_type(4))) float f32x4;
typedef __attribute__((ext_vector_type(4))) unsigned u32x4;

// order-preserving float->u32 encoding for atomicMax scatter-max
__device__ __forceinline__ unsigned enc(float f) {
    unsigned u = __float_as_uint(f);
    return u ^ (unsigned)(((int)u >> 31) | 0x80000000);
}
__device__ __forceinline__ float dec(unsigned u) {
    unsigned v = (u & 0x80000000u) ? (u & 0x7FFFFFFFu) : ~u;
    return __uint_as_float(v);
}
__device__ __forceinline__ unsigned short f2bf(float f) {   // RNE (cold path)
    unsigned u = __float_as_uint(f);
    u += 0x7fffu + ((u >> 16) & 1u);
    return (unsigned short)(u >> 16);
}
__device__ __forceinline__ unsigned pk2(float a, float b) { // v_cvt_pk_bf16_f32
    __hip_bfloat162 t = __float22bfloat162_rn(make_float2(a, b));
    unsigned r;
    __builtin_memcpy(&r, &t, 4);
    return r;
}

__global__ void decode_acc(unsigned* __restrict__ acc, int n) {
    int i = blockIdx.x * blockDim.x + threadIdx.x;
    if (i < n) {
        unsigned u = acc[i];
        ((float*)acc)[i] = (u == 0u) ? 0.0f : dec(u);   // empty -> 0.0 (ref)
    }
}

// 256 threads = 4 waves. Wave (w_h, w_e). Raw s_barrier (2/tile) + register
// prefetch of next tile's gather. __launch_bounds__(256,4): 4 waves/EU ->
// 4 blocks/CU resident (grid 1024 = 256 CU x 4), doubling latency hiding
// vs the (256,2) variant measured at 295 us / 21% occupancy.
__global__ __launch_bounds__(256, 4)
void edge_mlp(const float* __restrict__ x1, const float* __restrict__ x2,
              const int* __restrict__ ei1, const int* __restrict__ ei2,
              const float* __restrict__ W1, const float* __restrict__ b1,
              const float* __restrict__ W2, const float* __restrict__ b2,
              unsigned* __restrict__ acc)
{
    __shared__ short e_lds[64 * 128];   // 16 KB, (e&15) XOR-swizzled
    __shared__ short h_lds[64 * 128];   // 16 KB, same swizzle
    __shared__ int srow[2][64];         // double-buffered

    const int tid  = threadIdx.x;
    const int lane = tid & 63;
    const int l15  = lane & 15;
    const int lg   = lane >> 4;
    const int wid  = tid >> 6;
    const int w_h  = wid & 1;
    const int w_e  = wid >> 1;

    const int g     = (blockIdx.x >= BPG) ? 1 : 0;
    const int bslot = blockIdx.x & (BPG - 1);
    const int* __restrict__ ei = g ? ei2 : ei1;
    const float* __restrict__ xc = g ? x2 : x1;
    const int goff = g * 64;

    // ---- persistent register weights ----
    bf16x8 a1[4][4];                    // W1^T A-frags [m: hid][s: kstep]
    #pragma unroll
    for (int m = 0; m < 4; ++m)
        #pragma unroll
        for (int s = 0; s < 4; ++s) {
            const float* p = W1 + (size_t)(32 * s + 8 * lg) * 128
                               + (w_h * 64 + 16 * m + l15);
            bf16x8 r;
            #pragma unroll
            for (int i = 0; i < 8; ++i) r[i] = (short)f2bf(p[i * 128]);
            a1[m][s] = r;
        }
    bf16x8 b2f[4][2];                   // W2 B-frags [s: kstep][n: out]
    #pragma unroll
    for (int s = 0; s < 4; ++s)
        #pragma unroll
        for (int n = 0; n < 2; ++n) {
            const float* p = W2 + (size_t)(32 * s + 8 * lg) * 64
                               + (w_h * 32 + 16 * n + l15);
            bf16x8 r;
            #pragma unroll
            for (int i = 0; i < 8; ++i) r[i] = (short)f2bf(p[i * 64]);
            b2f[s][n] = r;
        }
    float4 b1v[4];
    #pragma unroll
    for (int m = 0; m < 4; ++m)
        b1v[m] = *(const float4*)(b1 + w_h * 64 + 16 * m + 4 * lg);
    float b2v[2];
    #pragma unroll
    for (int n = 0; n < 2; ++n) b2v[n] = b2[w_h * 32 + 16 * n + l15];

    // ---- gather mapping: this thread owns edge ge, float cols 16*gq..+15 ----
    const int ge = lane;
    const int gq = wid;                 // column quarter
    const int swz = (ge & 15) << 3;     // XOR swizzle, in shorts

    // ---- prologue: idx(t0), idx(t1), issue gather(t0) ----
    int rcur, ccur, rnext, cnext;
    {
        int ta = bslot;
        rcur = ei[ta * 64 + ge];
        ccur = ei[EE + ta * 64 + ge];
        int tb = ta + BPG; if (tb >= NTILES) tb = NTILES - 1;
        rnext = ei[tb * 64 + ge];
        cnext = ei[EE + tb * 64 + ge];
    }
    float4 gp0, gp1, gp2, gp3, gq0, gq1, gq2, gq3;
    {
        const float4* pp = (const float4*)(x1 + (size_t)rcur * 64 + 16 * gq);
        const float4* pq = (const float4*)(xc + (size_t)ccur * 64 + 16 * gq);
        gp0 = pp[0]; gp1 = pp[1]; gp2 = pp[2]; gp3 = pp[3];
        gq0 = pq[0]; gq1 = pq[1]; gq2 = pq[2]; gq3 = pq[3];
    }

    int i = 0;
    for (int t = bslot; t < NTILES; t += BPG, ++i) {
        // ---- A: write e tile (t) from prefetched regs; srow ----
        if (tid < 64) srow[i & 1][tid] = rcur;
        {
            short* erow = &e_lds[ge * 128];
            u32x4 v;
            v[0] = pk2(gp0.x, gp0.y); v[1] = pk2(gp0.z, gp0.w);
            v[2] = pk2(gp1.x, gp1.y); v[3] = pk2(gp1.z, gp1.w);
            *(u32x4*)&erow[(16 * gq) ^ swz] = v;
            v[0] = pk2(gp2.x, gp2.y); v[1] = pk2(gp2.z, gp2.w);
            v[2] = pk2(gp3.x, gp3.y); v[3] = pk2(gp3.z, gp3.w);
            *(u32x4*)&erow[(16 * gq + 8) ^ swz] = v;
            v[0] = pk2(gq0.x - gp0.x, gq0.y - gp0.y);
            v[1] = pk2(gq0.z - gp0.z, gq0.w - gp0.w);
            v[2] = pk2(gq1.x - gp1.x, gq1.y - gp1.y);
            v[3] = pk2(gq1.z - gp1.z, gq1.w - gp1.w);
            *(u32x4*)&erow[(64 + 16 * gq) ^ swz] = v;
            v[0] = pk2(gq2.x - gp2.x, gq2.y - gp2.y);
            v[1] = pk2(gq2.z - gp2.z, gq2.w - gp2.w);
            v[2] = pk2(gq3.x - gp3.x, gq3.y - gp3.y);
            v[3] = pk2(gq3.z - gp3.z, gq3.w - gp3.w);
            *(u32x4*)&erow[(64 + 16 * gq + 8) ^ swz] = v;
        }

        // ---- B: rotate idx; prefetch idx(t+2); issue gather(t+1) ----
        rcur = rnext; ccur = cnext;
        {
            int t2 = t + 2 * BPG; if (t2 >= NTILES) t2 = NTILES - 1;
            rnext = ei[t2 * 64 + ge];
            cnext = ei[EE + t2 * 64 + ge];
        }
        if (t + BPG < NTILES) {
            const float4* pp = (const float4*)(x1 + (size_t)rcur * 64 + 16 * gq);
            const float4* pq = (const float4*)(xc + (size_t)ccur * 64 + 16 * gq);
            gp0 = pp[0]; gp1 = pp[1]; gp2 = pp[2]; gp3 = pp[3];
            gq0 = pq[0]; gq1 = pq[1]; gq2 = pq[2]; gq3 = pq[3];
        }

        // ---- C: LDS visible, raw barrier (no vmcnt drain) ----
        asm volatile("s_waitcnt lgkmcnt(0)\n\ts_barrier" ::: "memory");

        // ---- D: layer 1 MFMA, relu, h write ----
        f32x4 acc1[4][2];
        #pragma unroll
        for (int m = 0; m < 4; ++m)
            #pragma unroll
            for (int n = 0; n < 2; ++n) {
                acc1[m][n][0] = b1v[m].x; acc1[m][n][1] = b1v[m].y;
                acc1[m][n][2] = b1v[m].z; acc1[m][n][3] = b1v[m].w;
            }
        __builtin_amdgcn_s_setprio(1);
        #pragma unroll
        for (int s = 0; s < 4; ++s) {
            bf16x8 eb[2];
            #pragma unroll
            for (int n = 0; n < 2; ++n) {
                int e = w_e * 32 + 16 * n + l15;
                int sidx = e * 128 + ((32 * s + 8 * lg) ^ ((e & 15) << 3));
                eb[n] = *(const bf16x8*)&e_lds[sidx];
            }
            #pragma unroll
            for (int m = 0; m < 4; ++m)
                #pragma unroll
                for (int n = 0; n < 2; ++n)
                    acc1[m][n] = __builtin_amdgcn_mfma_f32_16x16x32_bf16(
                        a1[m][s], eb[n], acc1[m][n], 0, 0, 0);
        }
        __builtin_amdgcn_s_setprio(0);
        #pragma unroll
        for (int m = 0; m < 4; ++m)
            #pragma unroll
            for (int n = 0; n < 2; ++n) {
                f32x4 vv = acc1[m][n];
                int e = w_e * 32 + 16 * n + l15;
                int hidc = w_h * 64 + 16 * m + 4 * lg;
                int sidx = e * 128 + (hidc ^ ((e & 15) << 3));
                uint2 w;
                w.x = pk2(fmaxf(vv[0], 0.f), fmaxf(vv[1], 0.f));
                w.y = pk2(fmaxf(vv[2], 0.f), fmaxf(vv[3], 0.f));
                *(uint2*)&h_lds[sidx] = w;
            }

        // ---- E: h visible, raw barrier ----
        asm volatile("s_waitcnt lgkmcnt(0)\n\ts_barrier" ::: "memory");

        // ---- F: layer 2 MFMA + scatter-max ----
        f32x4 acc2[2][2];
        #pragma unroll
        for (int m = 0; m < 2; ++m)
            #pragma unroll
            for (int n = 0; n < 2; ++n) {
                acc2[m][n][0] = b2v[n]; acc2[m][n][1] = b2v[n];
                acc2[m][n][2] = b2v[n]; acc2[m][n][3] = b2v[n];
            }
        __builtin_amdgcn_s_setprio(1);
        #pragma unroll
        for (int s = 0; s < 4; ++s) {
            bf16x8 ha[2];
            #pragma unroll
            for (int m = 0; m < 2; ++m) {
                int e = w_e * 32 + 16 * m + l15;
                int sidx = e * 128 + ((32 * s + 8 * lg) ^ ((e & 15) << 3));
                ha[m] = *(const bf16x8*)&h_lds[sidx];
            }
            #pragma unroll
            for (int m = 0; m < 2; ++m)
                #pragma unroll
                for (int n = 0; n < 2; ++n)
                    acc2[m][n] = __builtin_amdgcn_mfma_f32_16x16x32_bf16(
                        ha[m], b2f[s][n], acc2[m][n], 0, 0, 0);
        }
        __builtin_amdgcn_s_setprio(0);
        #pragma unroll
        for (int m = 0; m < 2; ++m) {
            int4 rows = *(const int4*)&srow[i & 1][w_e * 32 + 16 * m + 4 * lg];
            #pragma unroll
            for (int n = 0; n < 2; ++n) {
                int outc = w_h * 32 + 16 * n + l15;
                atomicMax(&acc[(size_t)rows.x * 128 + goff + outc], enc(acc2[m][n][0]));
                atomicMax(&acc[(size_t)rows.y * 128 + goff + outc], enc(acc2[m][n][1]));
                atomicMax(&acc[(size_t)rows.z * 128 + goff + outc], enc(acc2[m][n][2]));
                atomicMax(&acc[(size_t)rows.w * 128 + goff + outc], enc(acc2[m][n][3]));
            }
        }
    }
}

extern "C" void kernel_launch(void* const* d_in, const int* in_sizes, int n_in,
                              void* d_out, int out_size, void* d_ws, size_t ws_size,
                              hipStream_t stream) {
    const float* x1 = (const float*)d_in[0];
    const float* x2 = (const float*)d_in[1];
    const int*   ei1 = (const int*)d_in[2];
    const int*   ei2 = (const int*)d_in[3];
    const float* W1 = (const float*)d_in[4];
    const float* b1 = (const float*)d_in[5];
    const float* W2 = (const float*)d_in[6];
    const float* b2 = (const float*)d_in[7];
    unsigned* acc = (unsigned*)d_out;

    const int total = NN * 128;
    hipMemsetAsync(acc, 0, (size_t)total * sizeof(unsigned), stream);
    hipLaunchKernelGGL(edge_mlp, dim3(2 * BPG), dim3(256), 0, stream,
                       x1, x2, ei1, ei2, W1, b1, W2, b2, acc);
    hipLaunchKernelGGL(decode_acc, dim3((total + 255) / 256), dim3(256), 0, stream,
                       acc, total);
}

// Round 11
// 352.203 us; speedup vs baseline: 1.7543x; 1.7543x over previous
//
#include <hip/hip_runtime.h>

#define NN 50000
#define EE 800000
#define NTILES 12500
#define BPG 512                     // edge_mlp blocks per graph
#define NPB 196                     // pre_k blocks per job (196*256 >= 50000)

typedef _Float16 half8 __attribute__((ext_vector_type(8)));
typedef __attribute__((ext_vector_type(4))) float f32x4;
typedef __attribute__((ext_vector_type(4))) unsigned u32x4;

// order-preserving float->u32 encoding for atomicMax scatter-max
__device__ __forceinline__ unsigned enc(float f) {
    unsigned u = __float_as_uint(f);
    return u ^ (unsigned)(((int)u >> 31) | 0x80000000);
}
__device__ __forceinline__ float dec(unsigned u) {
    unsigned v = (u & 0x80000000u) ? (u & 0x7FFFFFFFu) : ~u;
    return __uint_as_float(v);
}

__global__ void decode_acc(unsigned* __restrict__ acc, int n) {
    int i = blockIdx.x * blockDim.x + threadIdx.x;
    if (i < n) {
        unsigned u = acc[i];
        ((float*)acc)[i] = (u == 0u) ? 0.0f : dec(u);   // empty -> 0.0 (ref)
    }
}

// ---------------- node-level precompute GEMMs ----------------
// job 0: a1  = x1 @ (W1top - W1bot) + b1      [NN x 128] f16
// job 1: bb1 = x1 @ W1bot                     [NN x 128] f16
// job 2: bb2 = x2 @ W1bot                     [NN x 128] f16
// Then per edge: h = relu(a1[row] + bb[col]) — layer 1 done.
__global__ __launch_bounds__(256)
void pre_k(const float* __restrict__ x1, const float* __restrict__ x2,
           const float* __restrict__ W1, const float* __restrict__ b1,
           _Float16* __restrict__ pre)
{
    const int j  = blockIdx.x / NPB;            // job
    const int bb = blockIdx.x % NPB;
    const float* __restrict__ xs = (j == 2) ? x2 : x1;
    _Float16* __restrict__ out = pre + (size_t)j * NN * 128;

    const int lane = threadIdx.x & 63;
    const int w    = threadIdx.x >> 6;
    const int l15  = lane & 15;
    const int lg   = lane >> 4;
    const int rowbase = bb * 256 + w * 64;

    // A-frags: x rows (f32 -> f16), m=4 row frags x ks=2 k-steps (K=64)
    half8 af[4][2];
    #pragma unroll
    for (int m = 0; m < 4; ++m)
        #pragma unroll
        for (int ks = 0; ks < 2; ++ks) {
            int row = rowbase + 16 * m + l15;
            if (row > NN - 1) row = NN - 1;
            const float* p = xs + (size_t)row * 64 + 32 * ks + 8 * lg;
            half8 r;
            #pragma unroll
            for (int i = 0; i < 8; ++i) r[i] = (_Float16)p[i];
            af[m][ks] = r;
        }

    #pragma unroll 2
    for (int n = 0; n < 8; ++n) {
        // B-frags of W (from global; W1 is L2-resident)
        half8 bf[2];
        #pragma unroll
        for (int ks = 0; ks < 2; ++ks) {
            half8 r;
            #pragma unroll
            for (int i = 0; i < 8; ++i) {
                int k = 32 * ks + 8 * lg + i;
                int o = 16 * n + l15;
                float wv = (j == 0)
                    ? (W1[(size_t)k * 128 + o] - W1[(size_t)(64 + k) * 128 + o])
                    :  W1[(size_t)(64 + k) * 128 + o];
                r[i] = (_Float16)wv;
            }
            bf[ks] = r;
        }
        float binit = (j == 0) ? b1[16 * n + l15] : 0.0f;
        f32x4 acc[4];
        #pragma unroll
        for (int m = 0; m < 4; ++m) {
            acc[m][0] = binit; acc[m][1] = binit;
            acc[m][2] = binit; acc[m][3] = binit;
        }
        #pragma unroll
        for (int ks = 0; ks < 2; ++ks)
            #pragma unroll
            for (int m = 0; m < 4; ++m)
                acc[m] = __builtin_amdgcn_mfma_f32_16x16x32_f16(
                    af[m][ks], bf[ks], acc[m], 0, 0, 0);
        // D: col = 16n+l15, rows = rowbase+16m+4lg+r
        #pragma unroll
        for (int m = 0; m < 4; ++m)
            #pragma unroll
            for (int r = 0; r < 4; ++r) {
                int row = rowbase + 16 * m + 4 * lg + r;
                if (row < NN)
                    out[(size_t)row * 128 + 16 * n + l15] = (_Float16)acc[m][r];
            }
    }
}

// ---------------- main kernel: gather-add-relu + layer2 MFMA ----------------
// 256 threads = 4 waves (w_h = out half, w_e = edge half). ONE raw barrier per
// 64-edge tile; h_lds double-buffered; register prefetch of next tile's a/b.
__global__ __launch_bounds__(256, 2)
void edge_mlp(const _Float16* __restrict__ pre,
              const int* __restrict__ ei1, const int* __restrict__ ei2,
              const float* __restrict__ W2, const float* __restrict__ b2,
              unsigned* __restrict__ acc)
{
    __shared__ short h_lds[2][64 * 128];   // 2 x 16 KB, (e&15)<<3 XOR-swizzled
    __shared__ int srow[2][64];

    const int tid  = threadIdx.x;
    const int lane = tid & 63;
    const int l15  = lane & 15;
    const int lg   = lane >> 4;
    const int wid  = tid >> 6;
    const int w_h  = wid & 1;
    const int w_e  = wid >> 1;

    const int g     = (blockIdx.x >= BPG) ? 1 : 0;
    const int bslot = blockIdx.x & (BPG - 1);
    const int* __restrict__ ei = g ? ei2 : ei1;
    const _Float16* __restrict__ pa = pre;                          // a1
    const _Float16* __restrict__ pb = pre + (size_t)(1 + g) * NN * 128;
    const int goff = g * 64;

    // W2 B-frags in f16 (32 VGPR)
    half8 b2f[4][2];
    #pragma unroll
    for (int s = 0; s < 4; ++s)
        #pragma unroll
        for (int n = 0; n < 2; ++n) {
            const float* p = W2 + (size_t)(32 * s + 8 * lg) * 64
                               + (w_h * 32 + 16 * n + l15);
            half8 r;
            #pragma unroll
            for (int i = 0; i < 8; ++i) r[i] = (_Float16)p[i * 64];
            b2f[s][n] = r;
        }
    float b2v[2];
    #pragma unroll
    for (int n = 0; n < 2; ++n) b2v[n] = b2[w_h * 32 + 16 * n + l15];

    // gather mapping: thread owns edge ge, f16 channels 32*gq..+31
    const int ge = lane;
    const int gq = wid;
    const int swz = (ge & 15) << 3;

    // ---- prologue: idx(t0), idx(t1); issue gather(t0) ----
    int rcur, ccur, rnext, cnext;
    {
        int ta = bslot;
        rcur = ei[ta * 64 + ge];
        ccur = ei[EE + ta * 64 + ge];
        int tb = ta + BPG; if (tb >= NTILES) tb = NTILES - 1;
        rnext = ei[tb * 64 + ge];
        cnext = ei[EE + tb * 64 + ge];
    }
    uint4 ga0, ga1, ga2, ga3, gb0, gb1, gb2, gb3;
    {
        const uint4* ap = (const uint4*)(pa + (size_t)rcur * 128 + 32 * gq);
        const uint4* bp = (const uint4*)(pb + (size_t)ccur * 128 + 32 * gq);
        ga0 = ap[0]; ga1 = ap[1]; ga2 = ap[2]; ga3 = ap[3];
        gb0 = bp[0]; gb1 = bp[1]; gb2 = bp[2]; gb3 = bp[3];
    }

    const unsigned zu = 0u;
    int i = 0;
    for (int t = bslot; t < NTILES; t += BPG, ++i) {
        const int ib = i & 1;
        // ---- A: srow + h tile = relu(a + b) from prefetched regs ----
        if (tid < 64) srow[ib][tid] = rcur;
        {
            short* hrow = &h_lds[ib][ge * 128];
            u32x4 h;
            #define COMBINE(A, B, K)                                           \
                {                                                              \
                    unsigned s0, s1, s2, s3;                                   \
                    asm("v_pk_add_f16 %0, %1, %2" : "=v"(s0) : "v"(A.x), "v"(B.x)); \
                    asm("v_pk_add_f16 %0, %1, %2" : "=v"(s1) : "v"(A.y), "v"(B.y)); \
                    asm("v_pk_add_f16 %0, %1, %2" : "=v"(s2) : "v"(A.z), "v"(B.z)); \
                    asm("v_pk_add_f16 %0, %1, %2" : "=v"(s3) : "v"(A.w), "v"(B.w)); \
                    asm("v_pk_max_f16 %0, %1, %2" : "=v"(s0) : "v"(s0), "v"(zu));   \
                    asm("v_pk_max_f16 %0, %1, %2" : "=v"(s1) : "v"(s1), "v"(zu));   \
                    asm("v_pk_max_f16 %0, %1, %2" : "=v"(s2) : "v"(s2), "v"(zu));   \
                    asm("v_pk_max_f16 %0, %1, %2" : "=v"(s3) : "v"(s3), "v"(zu));   \
                    h[0] = s0; h[1] = s1; h[2] = s2; h[3] = s3;                \
                    *(u32x4*)&hrow[(32 * gq + 8 * K) ^ swz] = h;               \
                }
            COMBINE(ga0, gb0, 0)
            COMBINE(ga1, gb1, 1)
            COMBINE(ga2, gb2, 2)
            COMBINE(ga3, gb3, 3)
            #undef COMBINE
        }

        // ---- B: rotate idx; prefetch idx(t+2); issue gather(t+1) ----
        rcur = rnext; ccur = cnext;
        {
            int t2 = t + 2 * BPG; if (t2 >= NTILES) t2 = NTILES - 1;
            rnext = ei[t2 * 64 + ge];
            cnext = ei[EE + t2 * 64 + ge];
        }
        if (t + BPG < NTILES) {
            const uint4* ap = (const uint4*)(pa + (size_t)rcur * 128 + 32 * gq);
            const uint4* bp = (const uint4*)(pb + (size_t)ccur * 128 + 32 * gq);
            ga0 = ap[0]; ga1 = ap[1]; ga2 = ap[2]; ga3 = ap[3];
            gb0 = bp[0]; gb1 = bp[1]; gb2 = bp[2]; gb3 = bp[3];
        }

        // ---- C: h/srow visible; single barrier per tile ----
        asm volatile("s_waitcnt lgkmcnt(0)\n\ts_barrier" ::: "memory");

        // ---- D: layer 2 MFMA + scatter-max ----
        f32x4 acc2[2][2];
        #pragma unroll
        for (int m = 0; m < 2; ++m)
            #pragma unroll
            for (int n = 0; n < 2; ++n) {
                acc2[m][n][0] = b2v[n]; acc2[m][n][1] = b2v[n];
                acc2[m][n][2] = b2v[n]; acc2[m][n][3] = b2v[n];
            }
        __builtin_amdgcn_s_setprio(1);
        #pragma unroll
        for (int s = 0; s < 4; ++s) {
            half8 ha[2];
            #pragma unroll
            for (int m = 0; m < 2; ++m) {
                int e = w_e * 32 + 16 * m + l15;
                int sidx = e * 128 + ((32 * s + 8 * lg) ^ ((e & 15) << 3));
                ha[m] = *(const half8*)&h_lds[ib][sidx];
            }
            #pragma unroll
            for (int m = 0; m < 2; ++m)
                #pragma unroll
                for (int n = 0; n < 2; ++n)
                    acc2[m][n] = __builtin_amdgcn_mfma_f32_16x16x32_f16(
                        ha[m], b2f[s][n], acc2[m][n], 0, 0, 0);
        }
        __builtin_amdgcn_s_setprio(0);
        #pragma unroll
        for (int m = 0; m < 2; ++m) {
            int4 rows = *(const int4*)&srow[ib][w_e * 32 + 16 * m + 4 * lg];
            #pragma unroll
            for (int n = 0; n < 2; ++n) {
                int outc = w_h * 32 + 16 * n + l15;
                atomicMax(&acc[(size_t)rows.x * 128 + goff + outc], enc(acc2[m][n][0]));
                atomicMax(&acc[(size_t)rows.y * 128 + goff + outc], enc(acc2[m][n][1]));
                atomicMax(&acc[(size_t)rows.z * 128 + goff + outc], enc(acc2[m][n][2]));
                atomicMax(&acc[(size_t)rows.w * 128 + goff + outc], enc(acc2[m][n][3]));
            }
        }
    }
}

extern "C" void kernel_launch(void* const* d_in, const int* in_sizes, int n_in,
                              void* d_out, int out_size, void* d_ws, size_t ws_size,
                              hipStream_t stream) {
    const float* x1 = (const float*)d_in[0];
    const float* x2 = (const float*)d_in[1];
    const int*   ei1 = (const int*)d_in[2];
    const int*   ei2 = (const int*)d_in[3];
    const float* W1 = (const float*)d_in[4];
    const float* b1 = (const float*)d_in[5];
    const float* W2 = (const float*)d_in[6];
    const float* b2 = (const float*)d_in[7];
    unsigned* acc = (unsigned*)d_out;
    _Float16* pre = (_Float16*)d_ws;    // 3 x NN x 128 f16 = 38.4 MB

    const int total = NN * 128;
    hipMemsetAsync(acc, 0, (size_t)total * sizeof(unsigned), stream);
    hipLaunchKernelGGL(pre_k, dim3(3 * NPB), dim3(256), 0, stream,
                       x1, x2, W1, b1, pre);
    hipLaunchKernelGGL(edge_mlp, dim3(2 * BPG), dim3(256), 0, stream,
                       pre, ei1, ei2, W2, b2, acc);
    hipLaunchKernelGGL(decode_acc, dim3((total + 255) / 256), dim3(256), 0, stream,
                       acc, total);
}